// Round 8
// baseline (361.216 us; speedup 1.0000x reference)
//
#include <hip/hip_runtime.h>
#include <hip/hip_bf16.h>
#include <math.h>

// UniMP 2-layer TransformerConv. N=50000, E=800000, G=512, D=64 (edge 16).
// R14: agg unclamped-chunk retiling WIN (61.9->57.8).
// R15/R16: csr_index parallelization + dispatch merges ~neutral => gaps ~1us,
// kernel time is spread (no hidden rock). agg x2 = 117us is biggest known.
// R17: agg anomaly: Occ 51% @ VGPR40/no-LDS => block churn (12500 blocks x
// ~1.2us) + per-node prologue (16 wer loads etc) dominate. Fix: grid-stride
// persistent waves (2048 blocks, ~6 nodes/wave serially), wer preload hoisted
// out of the node loop (node-invariant). Bodies otherwise identical to R16.

typedef unsigned int uint32;
typedef unsigned short u16;
typedef __attribute__((ext_vector_type(8))) short short8;
typedef __attribute__((ext_vector_type(4))) float f32x4;

#define BW 64         // dsts per bucket
#define NBMAX 800     // max buckets (ceil(50000/64)=782)
#define CAP 1536      // max edges per bucket (mean 1024, sd 32 -> +16 sigma)
#define EPB 2048      // edges per block in bucket_append

__device__ __forceinline__ uint32 f2bf(float x) {
    uint32 u = __float_as_uint(x);
    u += 0x7fffu + ((u >> 16) & 1u);
    return u >> 16;
}
__device__ __forceinline__ float bf2f(u16 h) {
    return __uint_as_float(((uint32)h) << 16);
}

// ------------- bucketed CSR build pass 1 (+ fused ea->bf16) -------------

__global__ __launch_bounds__(256) void bucket_append(
    const int* __restrict__ dst, const int* __restrict__ src,
    int* __restrict__ bcount, uint2* __restrict__ buf,
    const float* __restrict__ ea, u16* __restrict__ ea16e, int E, int NB)
{
    __shared__ int hist[NBMAX], gbase[NBMAX], fill[NBMAX];
    int t = threadIdx.x;
    for (int b = t; b < NBMAX; b += 256) { hist[b] = 0; fill[b] = 0; }
    __syncthreads();
    int e0 = blockIdx.x * EPB;
    int d[8], s[8];
    #pragma unroll
    for (int k = 0; k < 8; ++k) {
        int e = e0 + k * 256 + t;
        if (e < E) {
            d[k] = dst[e]; s[k] = src[e];
            atomicAdd(&hist[d[k] >> 6], 1);
            // fused ea -> bf16 convert (coalesced read + write)
            const float4* ev = (const float4*)(ea + (size_t)e * 16);
            float4 q0 = ev[0], q1 = ev[1], q2 = ev[2], q3 = ev[3];
            uint32* o = (uint32*)(ea16e + (size_t)e * 16);
            o[0] = f2bf(q0.x) | (f2bf(q0.y) << 16);
            o[1] = f2bf(q0.z) | (f2bf(q0.w) << 16);
            o[2] = f2bf(q1.x) | (f2bf(q1.y) << 16);
            o[3] = f2bf(q1.z) | (f2bf(q1.w) << 16);
            o[4] = f2bf(q2.x) | (f2bf(q2.y) << 16);
            o[5] = f2bf(q2.z) | (f2bf(q2.w) << 16);
            o[6] = f2bf(q3.x) | (f2bf(q3.y) << 16);
            o[7] = f2bf(q3.z) | (f2bf(q3.w) << 16);
        } else d[k] = -1;
    }
    __syncthreads();
    for (int b = t; b < NB; b += 256)
        if (hist[b] > 0) gbase[b] = atomicAdd(&bcount[b], hist[b]);
    __syncthreads();
    #pragma unroll
    for (int k = 0; k < 8; ++k) {
        if (d[k] >= 0) {
            int e = e0 + k * 256 + t;
            int b = d[k] >> 6;
            int off = atomicAdd(&fill[b], 1);
            buf[(size_t)b * CAP + gbase[b] + off] =
                make_uint2(((uint32)(d[k] & 63) << 20) | (uint32)e, (uint32)s[k]);
        }
    }
}

// one block per 64-dst bucket: inline prefix reduction + row_ptr +
// LDS-staged (s,e) -> coalesced csr_se
__global__ __launch_bounds__(256) void csr_index(
    const int* __restrict__ bcount, const uint2* __restrict__ buf,
    int* __restrict__ row_ptr, uint2* __restrict__ csr_se, int N, int E, int NB)
{
    __shared__ int lh[BW], lo[BW], fill[BW];
    __shared__ int wsum[4];
    __shared__ uint2 se[CAP];
    int t = threadIdx.x;
    int b = blockIdx.x;
    int lane = t & 63, wave = t >> 6;

    // base = sum(bcount[0..b)) -- strided partial + wave + LDS reduce
    int partial = 0;
    for (int i = t; i < b; i += 256) partial += bcount[i];
    #pragma unroll
    for (int off = 1; off < 64; off <<= 1) partial += __shfl_xor(partial, off);
    if (lane == 0) wsum[wave] = partial;
    if (t < BW) { lh[t] = 0; fill[t] = 0; }
    __syncthreads();
    int base = wsum[0] + wsum[1] + wsum[2] + wsum[3];
    int cnt = bcount[b];

    const uint2* bb = buf + (size_t)b * CAP;
    for (int i = t; i < cnt; i += 256) atomicAdd(&lh[(int)(bb[i].x >> 20)], 1);
    __syncthreads();
    // 64-wide exclusive scan of lh -> lo
    if (t < BW) lo[t] = lh[t];
    __syncthreads();
    for (int off = 1; off < BW; off <<= 1) {
        int add = (t < BW && t >= off) ? lo[t - off] : 0;
        __syncthreads();
        if (t < BW) lo[t] += add;
        __syncthreads();
    }
    if (t < BW) {
        int ex = lo[t] - lh[t];
        int node = b * BW + t;
        if (node < N) row_ptr[node] = base + ex;
        lo[t] = ex;
    }
    if (b == 0 && t == 0) row_ptr[N] = E;
    __syncthreads();
    for (int i = t; i < cnt; i += 256) {
        uint2 ent = bb[i];
        int dl = (int)(ent.x >> 20);
        int off = atomicAdd(&fill[dl], 1);
        se[lo[dl] + off] = make_uint2(ent.y, ent.x & 0xFFFFFu);   // (s, e)
    }
    __syncthreads();
    for (int i = t; i < cnt; i += 256) csr_se[base + i] = se[i];   // coalesced
}

// ---- weight prep: transpose + bf16 for MFMA B-frags; also zeroes bcount ----

__global__ void wprep_kernel(
    const float* __restrict__ wq1, const float* __restrict__ bq1,
    const float* __restrict__ wk1, const float* __restrict__ wv1,
    const float* __restrict__ ws1, const float* __restrict__ we1,
    const float* __restrict__ wq2, const float* __restrict__ bq2,
    const float* __restrict__ wk2, const float* __restrict__ wv2,
    const float* __restrict__ ws2, const float* __restrict__ we2,
    u16* __restrict__ wt1, float* __restrict__ be1,
    u16* __restrict__ wt2, float* __restrict__ be2,
    int* __restrict__ bcount)
{
    int L = blockIdx.x;
    const float* wq = L ? wq2 : wq1;
    const float* bq = L ? bq2 : bq1;
    const float* wk = L ? wk2 : wk1;
    const float* wv = L ? wv2 : wv1;
    const float* ws = L ? ws2 : ws1;
    const float* we = L ? we2 : we1;
    u16* wt = L ? wt2 : wt1;
    float* be = L ? be2 : be1;
    int t = threadIdx.x;
    if (L == 0) {
        for (int i = t; i < NBMAX; i += 256) bcount[i] = 0;
    }
    for (int i = t; i < 4096; i += 256) {
        int k = i >> 6, n = i & 63;
        wt[0 * 4096 + n * 64 + k] = (u16)f2bf(wq[k * 64 + n]);
        wt[1 * 4096 + n * 64 + k] = (u16)f2bf(wk[k * 64 + n]);
        wt[2 * 4096 + n * 64 + k] = (u16)f2bf(wv[k * 64 + n]);
        wt[3 * 4096 + n * 64 + k] = (u16)f2bf(ws[k * 64 + n]);
    }
    for (int i = t; i < 1024; i += 256) {
        int j = i >> 6, k = i & 63;
        float acc = 0.f;
        for (int c = 0; c < 64; ++c) acc = fmaf(wq[k * 64 + c], we[j * 64 + c], acc);
        wt[4 * 4096 + j * 64 + k] = (u16)f2bf(acc * 0.125f);
    }
    if (t < 16) {
        float acc = 0.f;
        for (int c = 0; c < 64; ++c) acc = fmaf(bq[c], we[t * 64 + c], acc);
        be[t] = acc * 0.125f;
    }
}

// ---- MFMA fused node linears (no LDS); optionally zeroes zbuf (pooled) ----

__global__ __launch_bounds__(256) void qkvs_mfma(
    const float* __restrict__ xin, const u16* __restrict__ wt,
    const float* __restrict__ bq, const float* __restrict__ bk,
    const float* __restrict__ bv, const float* __restrict__ bs,
    const float* __restrict__ be,
    float* __restrict__ qo, uint32* __restrict__ kvo,
    float* __restrict__ so, float* __restrict__ qeo, int N,
    float* __restrict__ zbuf, int zn)
{
    if (zbuf) {
        for (int i = blockIdx.x * 256 + threadIdx.x; i < zn; i += gridDim.x * 256)
            zbuf[i] = 0.f;
    }
    int wave = threadIdx.x >> 6;
    int lane = threadIdx.x & 63;
    int quad = lane >> 4;
    int l16 = lane & 15;
    int n0 = blockIdx.x * 64 + wave * 16;
    int row = n0 + l16;
    int rn = (row < N) ? row : (N - 1);

    const float4* xr = (const float4*)(xin + (size_t)rn * 64);
    float4 u0 = xr[quad * 2 + 0], u1 = xr[quad * 2 + 1];
    float4 u2 = xr[8 + quad * 2 + 0], u3 = xr[8 + quad * 2 + 1];
    short8 a0, a1;
    a0[0] = (short)f2bf(u0.x); a0[1] = (short)f2bf(u0.y);
    a0[2] = (short)f2bf(u0.z); a0[3] = (short)f2bf(u0.w);
    a0[4] = (short)f2bf(u1.x); a0[5] = (short)f2bf(u1.y);
    a0[6] = (short)f2bf(u1.z); a0[7] = (short)f2bf(u1.w);
    a1[0] = (short)f2bf(u2.x); a1[1] = (short)f2bf(u2.y);
    a1[2] = (short)f2bf(u2.z); a1[3] = (short)f2bf(u2.w);
    a1[4] = (short)f2bf(u3.x); a1[5] = (short)f2bf(u3.y);
    a1[6] = (short)f2bf(u3.z); a1[7] = (short)f2bf(u3.w);

    const short8* w8 = (const short8*)wt;

    f32x4 acc[4][4];
    #pragma unroll
    for (int m = 0; m < 4; ++m)
        #pragma unroll
        for (int c = 0; c < 4; ++c) acc[m][c] = (f32x4){0.f, 0.f, 0.f, 0.f};
    f32x4 aqe = (f32x4){0.f, 0.f, 0.f, 0.f};

    #pragma unroll
    for (int m = 0; m < 4; ++m) {
        #pragma unroll
        for (int c = 0; c < 4; ++c) {
            short8 b0 = w8[m * 512 + (c * 16 + l16) * 8 + quad];
            short8 b1 = w8[m * 512 + (c * 16 + l16) * 8 + 4 + quad];
            acc[m][c] = __builtin_amdgcn_mfma_f32_16x16x32_bf16(a0, b0, acc[m][c], 0, 0, 0);
            acc[m][c] = __builtin_amdgcn_mfma_f32_16x16x32_bf16(a1, b1, acc[m][c], 0, 0, 0);
        }
    }
    {
        short8 b0 = w8[4 * 512 + l16 * 8 + quad];
        short8 b1 = w8[4 * 512 + l16 * 8 + 4 + quad];
        aqe = __builtin_amdgcn_mfma_f32_16x16x32_bf16(a0, b0, aqe, 0, 0, 0);
        aqe = __builtin_amdgcn_mfma_f32_16x16x32_bf16(a1, b1, aqe, 0, 0, 0);
    }

    int node0 = n0 + quad * 4;
    #pragma unroll
    for (int c = 0; c < 4; ++c) {
        int col = c * 16 + l16;
        float bQ = bq[col], bK = bk[col], bV = bv[col], bS = bs[col];
        #pragma unroll
        for (int r = 0; r < 4; ++r) {
            int node = node0 + r;
            if (node < N) {
                size_t off = (size_t)node * 64 + col;
                qo[off] = (acc[0][c][r] + bQ) * 0.125f;
                kvo[off] = f2bf(acc[1][c][r] + bK) | (f2bf(acc[2][c][r] + bV) << 16);
                so[off] = acc[3][c][r] + bS;
            }
        }
    }
    float beL = be[l16];
    #pragma unroll
    for (int r = 0; r < 4; ++r) {
        int node = node0 + r;
        if (node < N) qeo[(size_t)node * 16 + l16] = aqe[r] + beL;
    }
}

// ---- per-node softmax aggregation: grid-stride persistent waves ----
// wer preload hoisted (node-invariant); per-node body = R16's unclamped
// full chunks + 4-edge tail.

__global__ __launch_bounds__(256) void agg_kernel(
    const float* __restrict__ q, const uint32* __restrict__ kv,
    const float* __restrict__ qe, const float* __restrict__ we,
    const u16* __restrict__ ea16e,
    const int* __restrict__ row_ptr, const uint2* __restrict__ csr_se,
    const float* __restrict__ skip_in, float* __restrict__ hout,
    const int* __restrict__ batch, float* __restrict__ pooled, int N)
{
    int lane = threadIdx.x & 63;
    int wave0 = (blockIdx.x << 2) + (threadIdx.x >> 6);
    int nwaves = gridDim.x << 2;

    int grp = lane >> 4;
    int pos = lane & 15;

    float wer[16];
    #pragma unroll
    for (int j = 0; j < 16; ++j) wer[j] = we[j * 64 + lane];

    for (int ii = wave0; ii < N; ii += nwaves) {
        int i = __builtin_amdgcn_readfirstlane(ii);

        float skip = skip_in[(size_t)i * 64 + lane];
        float4 qv = ((const float4*)(q + (size_t)i * 64))[pos];
        float qel = qe[(size_t)i * 16 + pos];

        float den = 0.f, aj = 0.f;
        float o4x = 0.f, o4y = 0.f, o4z = 0.f, o4w = 0.f;

        int beg = row_ptr[i], end = row_ptr[i + 1];
        int deg = end - beg;
        int nfull = deg >> 4;
        int p = beg;

        // ---- full 16-edge chunks: no clamping, no select ----
        for (int f = 0; f < nfull; ++f, p += 16) {
            #pragma unroll
            for (int c = 0; c < 4; ++c) {
                uint2 se = csr_se[p + 4 * c + grp];
                uint4 kb = ((const uint4*)(kv + (size_t)se.x * 64))[pos];
                float eav = bf2f(ea16e[(size_t)se.y * 16 + pos]);
                float pa = eav * qel;
                pa = fmaf(qv.x, __uint_as_float(kb.x << 16), pa);
                pa = fmaf(qv.y, __uint_as_float(kb.y << 16), pa);
                pa = fmaf(qv.z, __uint_as_float(kb.z << 16), pa);
                pa = fmaf(qv.w, __uint_as_float(kb.w << 16), pa);
                pa += __shfl_xor(pa, 1);
                pa += __shfl_xor(pa, 2);
                pa += __shfl_xor(pa, 4);
                pa += __shfl_xor(pa, 8);
                float w = __expf(pa);
                den += w;
                aj = fmaf(w, eav, aj);
                o4x = fmaf(w, __uint_as_float(kb.x & 0xffff0000u), o4x);
                o4y = fmaf(w, __uint_as_float(kb.y & 0xffff0000u), o4y);
                o4z = fmaf(w, __uint_as_float(kb.z & 0xffff0000u), o4z);
                o4w = fmaf(w, __uint_as_float(kb.w & 0xffff0000u), o4w);
            }
        }

        // ---- tail: 4 edges per step (one per 16-lane group), clamped ----
        int rem = deg & 15;
        if (rem) {
            int last = end - 1;
            int tsteps = (rem + 3) >> 2;
            for (int s = 0; s < tsteps; ++s) {
                int eg = p + 4 * s + grp;
                int si = (eg < end) ? eg : last;
                uint2 se = csr_se[si];
                uint4 kb = ((const uint4*)(kv + (size_t)se.x * 64))[pos];
                float eav = bf2f(ea16e[(size_t)se.y * 16 + pos]);
                float pa = eav * qel;
                pa = fmaf(qv.x, __uint_as_float(kb.x << 16), pa);
                pa = fmaf(qv.y, __uint_as_float(kb.y << 16), pa);
                pa = fmaf(qv.z, __uint_as_float(kb.z << 16), pa);
                pa = fmaf(qv.w, __uint_as_float(kb.w << 16), pa);
                pa += __shfl_xor(pa, 1);
                pa += __shfl_xor(pa, 2);
                pa += __shfl_xor(pa, 4);
                pa += __shfl_xor(pa, 8);
                float sc = (eg < end) ? pa : -1e30f;
                float w = __expf(sc);
                den += w;
                aj = fmaf(w, eav, aj);
                o4x = fmaf(w, __uint_as_float(kb.x & 0xffff0000u), o4x);
                o4y = fmaf(w, __uint_as_float(kb.y & 0xffff0000u), o4y);
                o4z = fmaf(w, __uint_as_float(kb.z & 0xffff0000u), o4z);
                o4w = fmaf(w, __uint_as_float(kb.w & 0xffff0000u), o4w);
            }
        }

        o4x += __shfl_xor(o4x, 16); o4x += __shfl_xor(o4x, 32);
        o4y += __shfl_xor(o4y, 16); o4y += __shfl_xor(o4y, 32);
        o4z += __shfl_xor(o4z, 16); o4z += __shfl_xor(o4z, 32);
        o4w += __shfl_xor(o4w, 16); o4w += __shfl_xor(o4w, 32);
        aj  += __shfl_xor(aj, 16);  aj  += __shfl_xor(aj, 32);
        den += __shfl_xor(den, 16); den += __shfl_xor(den, 32);

        int srcl = lane >> 2;
        float t0 = __shfl(o4x, srcl), t1 = __shfl(o4y, srcl);
        float t2 = __shfl(o4z, srcl), t3 = __shfl(o4w, srcl);
        int r2 = lane & 3;
        float o = (r2 == 0) ? t0 : (r2 == 1) ? t1 : (r2 == 2) ? t2 : t3;

        #pragma unroll
        for (int j = 0; j < 16; ++j) o = fmaf(__shfl(aj, j), wer[j], o);

        float dinv = (den > 0.f) ? 1.f / den : 0.f;
        float r = fmaf(o, dinv, skip);
        r = (r >= 0.f) ? r : 0.01f * r;
        hout[(size_t)i * 64 + lane] = r;
        if (pooled) atomicAdd(&pooled[(size_t)batch[i] * 64 + lane], r);
    }
}

// ---------------- head ----------------

__global__ void head_kernel(const float* __restrict__ pooled,
                            const float* __restrict__ w1, const float* __restrict__ b1,
                            const float* __restrict__ w2, const float* __restrict__ b2,
                            float* __restrict__ out, int G) {
    int g = blockIdx.x;
    int lane = threadIdx.x;
    __shared__ float hl[64];
    float p = pooled[g * 64 + lane];
    float ss = p * p;
    #pragma unroll
    for (int off = 32; off; off >>= 1) ss += __shfl_xor(ss, off);
    float hn = p / fmaxf(sqrtf(ss), 1e-12f);
    hl[lane] = hn;
    __syncthreads();
    float acc = b1[lane];
    #pragma unroll
    for (int j = 0; j < 64; ++j) acc = fmaf(hl[j], w1[j * 64 + lane], acc);
    acc = (acc >= 0.f) ? acc : 0.01f * acc;
    float r = acc * w2[lane];
    #pragma unroll
    for (int off = 32; off; off >>= 1) r += __shfl_xor(r, off);
    if (lane == 0) out[g] = r + b2[0];
}

// ---------------- launch ----------------

extern "C" void kernel_launch(void* const* d_in, const int* in_sizes, int n_in,
                              void* d_out, int out_size, void* d_ws, size_t ws_size,
                              hipStream_t stream) {
    const float* x     = (const float*)d_in[0];
    const int*   ei    = (const int*)  d_in[1];
    const float* ea    = (const float*)d_in[2];
    const int*   batch = (const int*)  d_in[3];
    const float *wq1=(const float*)d_in[4],  *bq1=(const float*)d_in[5];
    const float *wk1=(const float*)d_in[6],  *bk1=(const float*)d_in[7];
    const float *wv1=(const float*)d_in[8],  *bv1=(const float*)d_in[9];
    const float *we1=(const float*)d_in[10];
    const float *ws1=(const float*)d_in[11], *bs1=(const float*)d_in[12];
    const float *wq2=(const float*)d_in[13], *bq2=(const float*)d_in[14];
    const float *wk2=(const float*)d_in[15], *bk2=(const float*)d_in[16];
    const float *wv2=(const float*)d_in[17], *bv2=(const float*)d_in[18];
    const float *we2=(const float*)d_in[19];
    const float *ws2=(const float*)d_in[20], *bs2=(const float*)d_in[21];
    const float *wf1=(const float*)d_in[22], *bf1=(const float*)d_in[23];
    const float *wf2=(const float*)d_in[24], *bf2=(const float*)d_in[25];

    int N = in_sizes[0] / 64;
    int E = in_sizes[2] / 16;
    int G = out_size - N * 64;
    int NB = (N + BW - 1) / BW;

    const int* srcA = ei;
    const int* dstA = ei + E;

    char* w = (char*)d_ws;
    float*  qb      = (float*)w;  w += (size_t)N * 64 * 4;
    uint32* kvb     = (uint32*)w; w += (size_t)N * 64 * 4;
    float*  hb      = (float*)w;  w += (size_t)N * 64 * 4;
    float*  qeb     = (float*)w;  w += (size_t)N * 16 * 4;
    float*  pooled  = (float*)w;  w += (size_t)G * 64 * 4;
    int* bcount     = (int*)w;    w += NBMAX * 4;
    int* row_ptr    = (int*)w;    w += (size_t)(N + 1) * 4;
    u16* wt1        = (u16*)w;    w += (4 * 4096 + 1024) * 2;
    u16* wt2        = (u16*)w;    w += (4 * 4096 + 1024) * 2;
    float* be1      = (float*)w;  w += 16 * 4;
    float* be2      = (float*)w;  w += 16 * 4;
    uint2* csr_se   = (uint2*)w;  w += (size_t)E * 8;
    u16* ea16e      = (u16*)w;    w += ((size_t)E * 16 + 1024) * 2;
    uint2* bbuf     = (uint2*)w;  w += (size_t)NB * CAP * 8;

    float* outp = (float*)d_out;
    float* atom = outp + G;

    int eB = (E + EPB - 1) / EPB;
    int qBlocks = (N + 63) / 64;
    int aggBlocks = 2048;          // persistent: 8192 waves, ~6 nodes/wave

    // 8 dispatches, no memset:
    wprep_kernel<<<2, 256, 0, stream>>>(wq1, bq1, wk1, wv1, ws1, we1,
                                        wq2, bq2, wk2, wv2, ws2, we2,
                                        wt1, be1, wt2, be2, bcount);
    bucket_append<<<eB, 256, 0, stream>>>(dstA, srcA, bcount, bbuf,
                                          ea, ea16e, E, NB);
    csr_index<<<NB, 256, 0, stream>>>(bcount, bbuf, row_ptr, csr_se, N, E, NB);

    qkvs_mfma<<<qBlocks, 256, 0, stream>>>(x, wt1, bq1, bk1, bv1, bs1, be1,
                                           qb, kvb, hb, qeb, N, nullptr, 0);
    agg_kernel<<<aggBlocks, 256, 0, stream>>>(qb, kvb, qeb, we1, ea16e, row_ptr, csr_se,
                                              hb, hb, nullptr, nullptr, N);

    qkvs_mfma<<<qBlocks, 256, 0, stream>>>(hb, wt2, bq2, bk2, bv2, bs2, be2,
                                           qb, kvb, atom, qeb, N, pooled, G * 64);
    agg_kernel<<<aggBlocks, 256, 0, stream>>>(qb, kvb, qeb, we2, ea16e, row_ptr, csr_se,
                                              atom, atom, batch, pooled, N);

    head_kernel<<<G, 64, 0, stream>>>(pooled, wf1, bf1, wf2, bf2, outp, G);
}

// Round 10
// 339.184 us; speedup vs baseline: 1.0650x; 1.0650x over previous
//
#include <hip/hip_runtime.h>
#include <hip/hip_bf16.h>
#include <math.h>

// UniMP 2-layer TransformerConv. N=50000, E=800000, G=512, D=64 (edge 16).
// R14: agg unclamped-chunk retiling WIN (57.8). R15/R16: build parallelize +
// dispatch merges ~neutral (gaps ~1us). R17: persistent-wave agg REGRESSED
// (58.5->60.7, load imbalance) -> reverted; agg declared locally converged.
// R18: occupancy attack on the two under-decomposed pre-pass kernels:
//   - bucket_append EPB 2048->1024: 391 -> 782 blocks (3/CU) for the ~130MB
//     streaming + scatter work that was running at 1.5 blocks/CU.
//   - wprep 2 -> 64 blocks (sectioned); it is on the critical path (zeroes
//     bcount) and had a whole-GPU-idle serial inner loop.
// R19: resubmit of R18 (previous round was an infra failure, no measurement).

typedef unsigned int uint32;
typedef unsigned short u16;
typedef __attribute__((ext_vector_type(8))) short short8;
typedef __attribute__((ext_vector_type(4))) float f32x4;

#define BW 64         // dsts per bucket
#define NBMAX 800     // max buckets (ceil(50000/64)=782)
#define CAP 1536      // max edges per bucket (mean 1024, sd 32 -> +16 sigma)
#define EPB 1024      // edges per block in bucket_append (R18: was 2048)

__device__ __forceinline__ uint32 f2bf(float x) {
    uint32 u = __float_as_uint(x);
    u += 0x7fffu + ((u >> 16) & 1u);
    return u >> 16;
}
__device__ __forceinline__ float bf2f(u16 h) {
    return __uint_as_float(((uint32)h) << 16);
}

// ------------- bucketed CSR build pass 1 (+ fused ea->bf16) -------------

__global__ __launch_bounds__(256) void bucket_append(
    const int* __restrict__ dst, const int* __restrict__ src,
    int* __restrict__ bcount, uint2* __restrict__ buf,
    const float* __restrict__ ea, u16* __restrict__ ea16e, int E, int NB)
{
    __shared__ int hist[NBMAX], gbase[NBMAX], fill[NBMAX];
    int t = threadIdx.x;
    for (int b = t; b < NBMAX; b += 256) { hist[b] = 0; fill[b] = 0; }
    __syncthreads();
    int e0 = blockIdx.x * EPB;
    int d[4], s[4];
    #pragma unroll
    for (int k = 0; k < 4; ++k) {
        int e = e0 + k * 256 + t;
        if (e < E) {
            d[k] = dst[e]; s[k] = src[e];
            atomicAdd(&hist[d[k] >> 6], 1);
            // fused ea -> bf16 convert (coalesced read + write)
            const float4* ev = (const float4*)(ea + (size_t)e * 16);
            float4 q0 = ev[0], q1 = ev[1], q2 = ev[2], q3 = ev[3];
            uint32* o = (uint32*)(ea16e + (size_t)e * 16);
            o[0] = f2bf(q0.x) | (f2bf(q0.y) << 16);
            o[1] = f2bf(q0.z) | (f2bf(q0.w) << 16);
            o[2] = f2bf(q1.x) | (f2bf(q1.y) << 16);
            o[3] = f2bf(q1.z) | (f2bf(q1.w) << 16);
            o[4] = f2bf(q2.x) | (f2bf(q2.y) << 16);
            o[5] = f2bf(q2.z) | (f2bf(q2.w) << 16);
            o[6] = f2bf(q3.x) | (f2bf(q3.y) << 16);
            o[7] = f2bf(q3.z) | (f2bf(q3.w) << 16);
        } else d[k] = -1;
    }
    __syncthreads();
    for (int b = t; b < NB; b += 256)
        if (hist[b] > 0) gbase[b] = atomicAdd(&bcount[b], hist[b]);
    __syncthreads();
    #pragma unroll
    for (int k = 0; k < 4; ++k) {
        if (d[k] >= 0) {
            int e = e0 + k * 256 + t;
            int b = d[k] >> 6;
            int off = atomicAdd(&fill[b], 1);
            buf[(size_t)b * CAP + gbase[b] + off] =
                make_uint2(((uint32)(d[k] & 63) << 20) | (uint32)e, (uint32)s[k]);
        }
    }
}

// one block per 64-dst bucket: inline prefix reduction + row_ptr +
// LDS-staged (s,e) -> coalesced csr_se
__global__ __launch_bounds__(256) void csr_index(
    const int* __restrict__ bcount, const uint2* __restrict__ buf,
    int* __restrict__ row_ptr, uint2* __restrict__ csr_se, int N, int E, int NB)
{
    __shared__ int lh[BW], lo[BW], fill[BW];
    __shared__ int wsum[4];
    __shared__ uint2 se[CAP];
    int t = threadIdx.x;
    int b = blockIdx.x;
    int lane = t & 63, wave = t >> 6;

    // base = sum(bcount[0..b)) -- strided partial + wave + LDS reduce
    int partial = 0;
    for (int i = t; i < b; i += 256) partial += bcount[i];
    #pragma unroll
    for (int off = 1; off < 64; off <<= 1) partial += __shfl_xor(partial, off);
    if (lane == 0) wsum[wave] = partial;
    if (t < BW) { lh[t] = 0; fill[t] = 0; }
    __syncthreads();
    int base = wsum[0] + wsum[1] + wsum[2] + wsum[3];
    int cnt = bcount[b];

    const uint2* bb = buf + (size_t)b * CAP;
    for (int i = t; i < cnt; i += 256) atomicAdd(&lh[(int)(bb[i].x >> 20)], 1);
    __syncthreads();
    // 64-wide exclusive scan of lh -> lo
    if (t < BW) lo[t] = lh[t];
    __syncthreads();
    for (int off = 1; off < BW; off <<= 1) {
        int add = (t < BW && t >= off) ? lo[t - off] : 0;
        __syncthreads();
        if (t < BW) lo[t] += add;
        __syncthreads();
    }
    if (t < BW) {
        int ex = lo[t] - lh[t];
        int node = b * BW + t;
        if (node < N) row_ptr[node] = base + ex;
        lo[t] = ex;
    }
    if (b == 0 && t == 0) row_ptr[N] = E;
    __syncthreads();
    for (int i = t; i < cnt; i += 256) {
        uint2 ent = bb[i];
        int dl = (int)(ent.x >> 20);
        int off = atomicAdd(&fill[dl], 1);
        se[lo[dl] + off] = make_uint2(ent.y, ent.x & 0xFFFFFu);   // (s, e)
    }
    __syncthreads();
    for (int i = t; i < cnt; i += 256) csr_se[base + i] = se[i];   // coalesced
}

// ---- weight prep (64 blocks, sectioned): transpose + bf16 B-frags;
// fused we-products; zeroes bcount. L = bid&1, sec = bid>>1 (0..31).

__global__ __launch_bounds__(256) void wprep_kernel(
    const float* __restrict__ wq1, const float* __restrict__ bq1,
    const float* __restrict__ wk1, const float* __restrict__ wv1,
    const float* __restrict__ ws1, const float* __restrict__ we1,
    const float* __restrict__ wq2, const float* __restrict__ bq2,
    const float* __restrict__ wk2, const float* __restrict__ wv2,
    const float* __restrict__ ws2, const float* __restrict__ we2,
    u16* __restrict__ wt1, float* __restrict__ be1,
    u16* __restrict__ wt2, float* __restrict__ be2,
    int* __restrict__ bcount)
{
    int L = blockIdx.x & 1;
    int sec = blockIdx.x >> 1;        // 0..31
    const float* wq = L ? wq2 : wq1;
    const float* bq = L ? bq2 : bq1;
    const float* wk = L ? wk2 : wk1;
    const float* wv = L ? wv2 : wv1;
    const float* ws = L ? ws2 : ws1;
    const float* we = L ? we2 : we1;
    u16* wt = L ? wt2 : wt1;
    float* be = L ? be2 : be1;
    int t = threadIdx.x;

    if (L == 0) {
        int z = sec * 25 + t;
        if (t < 25 && z < NBMAX) bcount[z] = 0;
    }

    // transposes: 4 tables x 4096 = 16384 items / 32 secs = 512 items/sec
    const float* tabs[4] = { wq, wk, wv, ws };
    for (int r = 0; r < 2; ++r) {
        int id = sec * 512 + r * 256 + t;
        int tab = id >> 12, rem = id & 4095;
        int k = rem >> 6, n = rem & 63;
        wt[tab * 4096 + n * 64 + k] = (u16)f2bf(tabs[tab][k * 64 + n]);
    }

    // we-products: 1024 items / 32 secs = 32 items/sec (threads 0..31)
    if (t < 32) {
        int id = sec * 32 + t;
        int j = id >> 6, k = id & 63;
        float acc = 0.f;
        #pragma unroll
        for (int c = 0; c < 64; ++c) acc = fmaf(wq[k * 64 + c], we[j * 64 + c], acc);
        wt[4 * 4096 + j * 64 + k] = (u16)f2bf(acc * 0.125f);
    }
    if (sec == 0 && t >= 64 && t < 80) {
        int j = t - 64;
        float acc = 0.f;
        #pragma unroll
        for (int c = 0; c < 64; ++c) acc = fmaf(bq[c], we[j * 64 + c], acc);
        be[j] = acc * 0.125f;
    }
}

// ---- MFMA fused node linears (no LDS); optionally zeroes zbuf (pooled) ----

__global__ __launch_bounds__(256) void qkvs_mfma(
    const float* __restrict__ xin, const u16* __restrict__ wt,
    const float* __restrict__ bq, const float* __restrict__ bk,
    const float* __restrict__ bv, const float* __restrict__ bs,
    const float* __restrict__ be,
    float* __restrict__ qo, uint32* __restrict__ kvo,
    float* __restrict__ so, float* __restrict__ qeo, int N,
    float* __restrict__ zbuf, int zn)
{
    if (zbuf) {
        for (int i = blockIdx.x * 256 + threadIdx.x; i < zn; i += gridDim.x * 256)
            zbuf[i] = 0.f;
    }
    int wave = threadIdx.x >> 6;
    int lane = threadIdx.x & 63;
    int quad = lane >> 4;
    int l16 = lane & 15;
    int n0 = blockIdx.x * 64 + wave * 16;
    int row = n0 + l16;
    int rn = (row < N) ? row : (N - 1);

    const float4* xr = (const float4*)(xin + (size_t)rn * 64);
    float4 u0 = xr[quad * 2 + 0], u1 = xr[quad * 2 + 1];
    float4 u2 = xr[8 + quad * 2 + 0], u3 = xr[8 + quad * 2 + 1];
    short8 a0, a1;
    a0[0] = (short)f2bf(u0.x); a0[1] = (short)f2bf(u0.y);
    a0[2] = (short)f2bf(u0.z); a0[3] = (short)f2bf(u0.w);
    a0[4] = (short)f2bf(u1.x); a0[5] = (short)f2bf(u1.y);
    a0[6] = (short)f2bf(u1.z); a0[7] = (short)f2bf(u1.w);
    a1[0] = (short)f2bf(u2.x); a1[1] = (short)f2bf(u2.y);
    a1[2] = (short)f2bf(u2.z); a1[3] = (short)f2bf(u2.w);
    a1[4] = (short)f2bf(u3.x); a1[5] = (short)f2bf(u3.y);
    a1[6] = (short)f2bf(u3.z); a1[7] = (short)f2bf(u3.w);

    const short8* w8 = (const short8*)wt;

    f32x4 acc[4][4];
    #pragma unroll
    for (int m = 0; m < 4; ++m)
        #pragma unroll
        for (int c = 0; c < 4; ++c) acc[m][c] = (f32x4){0.f, 0.f, 0.f, 0.f};
    f32x4 aqe = (f32x4){0.f, 0.f, 0.f, 0.f};

    #pragma unroll
    for (int m = 0; m < 4; ++m) {
        #pragma unroll
        for (int c = 0; c < 4; ++c) {
            short8 b0 = w8[m * 512 + (c * 16 + l16) * 8 + quad];
            short8 b1 = w8[m * 512 + (c * 16 + l16) * 8 + 4 + quad];
            acc[m][c] = __builtin_amdgcn_mfma_f32_16x16x32_bf16(a0, b0, acc[m][c], 0, 0, 0);
            acc[m][c] = __builtin_amdgcn_mfma_f32_16x16x32_bf16(a1, b1, acc[m][c], 0, 0, 0);
        }
    }
    {
        short8 b0 = w8[4 * 512 + l16 * 8 + quad];
        short8 b1 = w8[4 * 512 + l16 * 8 + 4 + quad];
        aqe = __builtin_amdgcn_mfma_f32_16x16x32_bf16(a0, b0, aqe, 0, 0, 0);
        aqe = __builtin_amdgcn_mfma_f32_16x16x32_bf16(a1, b1, aqe, 0, 0, 0);
    }

    int node0 = n0 + quad * 4;
    #pragma unroll
    for (int c = 0; c < 4; ++c) {
        int col = c * 16 + l16;
        float bQ = bq[col], bK = bk[col], bV = bv[col], bS = bs[col];
        #pragma unroll
        for (int r = 0; r < 4; ++r) {
            int node = node0 + r;
            if (node < N) {
                size_t off = (size_t)node * 64 + col;
                qo[off] = (acc[0][c][r] + bQ) * 0.125f;
                kvo[off] = f2bf(acc[1][c][r] + bK) | (f2bf(acc[2][c][r] + bV) << 16);
                so[off] = acc[3][c][r] + bS;
            }
        }
    }
    float beL = be[l16];
    #pragma unroll
    for (int r = 0; r < 4; ++r) {
        int node = node0 + r;
        if (node < N) qeo[(size_t)node * 16 + l16] = aqe[r] + beL;
    }
}

// ---- per-node softmax aggregation (R16 exact): unclamped chunks + tail ----

__global__ __launch_bounds__(256) void agg_kernel(
    const float* __restrict__ q, const uint32* __restrict__ kv,
    const float* __restrict__ qe, const float* __restrict__ we,
    const u16* __restrict__ ea16e,
    const int* __restrict__ row_ptr, const uint2* __restrict__ csr_se,
    const float* __restrict__ skip_in, float* __restrict__ hout,
    const int* __restrict__ batch, float* __restrict__ pooled, int N)
{
    int lane = threadIdx.x & 63;
    int wid = (blockIdx.x << 2) + (threadIdx.x >> 6);
    if (wid >= N) return;
    int i = __builtin_amdgcn_readfirstlane(wid);

    int grp = lane >> 4;
    int pos = lane & 15;

    float skip = skip_in[(size_t)i * 64 + lane];      // hoisted: overlaps loop
    float4 qv = ((const float4*)(q + (size_t)i * 64))[pos];
    float qel = qe[(size_t)i * 16 + pos];
    float wer[16];
    #pragma unroll
    for (int j = 0; j < 16; ++j) wer[j] = we[j * 64 + lane];

    float den = 0.f, aj = 0.f;
    float o4x = 0.f, o4y = 0.f, o4z = 0.f, o4w = 0.f;

    int beg = row_ptr[i], end = row_ptr[i + 1];
    int deg = end - beg;
    int nfull = deg >> 4;
    int p = beg;

    // ---- full 16-edge chunks: no clamping, no select ----
    for (int f = 0; f < nfull; ++f, p += 16) {
        #pragma unroll
        for (int c = 0; c < 4; ++c) {
            uint2 se = csr_se[p + 4 * c + grp];
            uint4 kb = ((const uint4*)(kv + (size_t)se.x * 64))[pos];
            float eav = bf2f(ea16e[(size_t)se.y * 16 + pos]);
            float pa = eav * qel;
            pa = fmaf(qv.x, __uint_as_float(kb.x << 16), pa);
            pa = fmaf(qv.y, __uint_as_float(kb.y << 16), pa);
            pa = fmaf(qv.z, __uint_as_float(kb.z << 16), pa);
            pa = fmaf(qv.w, __uint_as_float(kb.w << 16), pa);
            pa += __shfl_xor(pa, 1);
            pa += __shfl_xor(pa, 2);
            pa += __shfl_xor(pa, 4);
            pa += __shfl_xor(pa, 8);
            float w = __expf(pa);
            den += w;
            aj = fmaf(w, eav, aj);
            o4x = fmaf(w, __uint_as_float(kb.x & 0xffff0000u), o4x);
            o4y = fmaf(w, __uint_as_float(kb.y & 0xffff0000u), o4y);
            o4z = fmaf(w, __uint_as_float(kb.z & 0xffff0000u), o4z);
            o4w = fmaf(w, __uint_as_float(kb.w & 0xffff0000u), o4w);
        }
    }

    // ---- tail: 4 edges per step (one per 16-lane group), clamped ----
    int rem = deg & 15;
    if (rem) {
        int last = end - 1;
        int tsteps = (rem + 3) >> 2;
        for (int s = 0; s < tsteps; ++s) {
            int eg = p + 4 * s + grp;
            int si = (eg < end) ? eg : last;
            uint2 se = csr_se[si];
            uint4 kb = ((const uint4*)(kv + (size_t)se.x * 64))[pos];
            float eav = bf2f(ea16e[(size_t)se.y * 16 + pos]);
            float pa = eav * qel;
            pa = fmaf(qv.x, __uint_as_float(kb.x << 16), pa);
            pa = fmaf(qv.y, __uint_as_float(kb.y << 16), pa);
            pa = fmaf(qv.z, __uint_as_float(kb.z << 16), pa);
            pa = fmaf(qv.w, __uint_as_float(kb.w << 16), pa);
            pa += __shfl_xor(pa, 1);
            pa += __shfl_xor(pa, 2);
            pa += __shfl_xor(pa, 4);
            pa += __shfl_xor(pa, 8);
            float sc = (eg < end) ? pa : -1e30f;
            float w = __expf(sc);
            den += w;
            aj = fmaf(w, eav, aj);
            o4x = fmaf(w, __uint_as_float(kb.x & 0xffff0000u), o4x);
            o4y = fmaf(w, __uint_as_float(kb.y & 0xffff0000u), o4y);
            o4z = fmaf(w, __uint_as_float(kb.z & 0xffff0000u), o4z);
            o4w = fmaf(w, __uint_as_float(kb.w & 0xffff0000u), o4w);
        }
    }

    o4x += __shfl_xor(o4x, 16); o4x += __shfl_xor(o4x, 32);
    o4y += __shfl_xor(o4y, 16); o4y += __shfl_xor(o4y, 32);
    o4z += __shfl_xor(o4z, 16); o4z += __shfl_xor(o4z, 32);
    o4w += __shfl_xor(o4w, 16); o4w += __shfl_xor(o4w, 32);
    aj  += __shfl_xor(aj, 16);  aj  += __shfl_xor(aj, 32);
    den += __shfl_xor(den, 16); den += __shfl_xor(den, 32);

    int srcl = lane >> 2;
    float t0 = __shfl(o4x, srcl), t1 = __shfl(o4y, srcl);
    float t2 = __shfl(o4z, srcl), t3 = __shfl(o4w, srcl);
    int r2 = lane & 3;
    float o = (r2 == 0) ? t0 : (r2 == 1) ? t1 : (r2 == 2) ? t2 : t3;

    #pragma unroll
    for (int j = 0; j < 16; ++j) o = fmaf(__shfl(aj, j), wer[j], o);

    float dinv = (den > 0.f) ? 1.f / den : 0.f;
    float r = fmaf(o, dinv, skip);
    r = (r >= 0.f) ? r : 0.01f * r;
    hout[(size_t)i * 64 + lane] = r;
    if (pooled) atomicAdd(&pooled[(size_t)batch[i] * 64 + lane], r);
}

// ---------------- head ----------------

__global__ void head_kernel(const float* __restrict__ pooled,
                            const float* __restrict__ w1, const float* __restrict__ b1,
                            const float* __restrict__ w2, const float* __restrict__ b2,
                            float* __restrict__ out, int G) {
    int g = blockIdx.x;
    int lane = threadIdx.x;
    __shared__ float hl[64];
    float p = pooled[g * 64 + lane];
    float ss = p * p;
    #pragma unroll
    for (int off = 32; off; off >>= 1) ss += __shfl_xor(ss, off);
    float hn = p / fmaxf(sqrtf(ss), 1e-12f);
    hl[lane] = hn;
    __syncthreads();
    float acc = b1[lane];
    #pragma unroll
    for (int j = 0; j < 64; ++j) acc = fmaf(hl[j], w1[j * 64 + lane], acc);
    acc = (acc >= 0.f) ? acc : 0.01f * acc;
    float r = acc * w2[lane];
    #pragma unroll
    for (int off = 32; off; off >>= 1) r += __shfl_xor(r, off);
    if (lane == 0) out[g] = r + b2[0];
}

// ---------------- launch ----------------

extern "C" void kernel_launch(void* const* d_in, const int* in_sizes, int n_in,
                              void* d_out, int out_size, void* d_ws, size_t ws_size,
                              hipStream_t stream) {
    const float* x     = (const float*)d_in[0];
    const int*   ei    = (const int*)  d_in[1];
    const float* ea    = (const float*)d_in[2];
    const int*   batch = (const int*)  d_in[3];
    const float *wq1=(const float*)d_in[4],  *bq1=(const float*)d_in[5];
    const float *wk1=(const float*)d_in[6],  *bk1=(const float*)d_in[7];
    const float *wv1=(const float*)d_in[8],  *bv1=(const float*)d_in[9];
    const float *we1=(const float*)d_in[10];
    const float *ws1=(const float*)d_in[11], *bs1=(const float*)d_in[12];
    const float *wq2=(const float*)d_in[13], *bq2=(const float*)d_in[14];
    const float *wk2=(const float*)d_in[15], *bk2=(const float*)d_in[16];
    const float *wv2=(const float*)d_in[17], *bv2=(const float*)d_in[18];
    const float *we2=(const float*)d_in[19];
    const float *ws2=(const float*)d_in[20], *bs2=(const float*)d_in[21];
    const float *wf1=(const float*)d_in[22], *bf1=(const float*)d_in[23];
    const float *wf2=(const float*)d_in[24], *bf2=(const float*)d_in[25];

    int N = in_sizes[0] / 64;
    int E = in_sizes[2] / 16;
    int G = out_size - N * 64;
    int NB = (N + BW - 1) / BW;

    const int* srcA = ei;
    const int* dstA = ei + E;

    char* w = (char*)d_ws;
    float*  qb      = (float*)w;  w += (size_t)N * 64 * 4;
    uint32* kvb     = (uint32*)w; w += (size_t)N * 64 * 4;
    float*  hb      = (float*)w;  w += (size_t)N * 64 * 4;
    float*  qeb     = (float*)w;  w += (size_t)N * 16 * 4;
    float*  pooled  = (float*)w;  w += (size_t)G * 64 * 4;
    int* bcount     = (int*)w;    w += NBMAX * 4;
    int* row_ptr    = (int*)w;    w += (size_t)(N + 1) * 4;
    u16* wt1        = (u16*)w;    w += (4 * 4096 + 1024) * 2;
    u16* wt2        = (u16*)w;    w += (4 * 4096 + 1024) * 2;
    float* be1      = (float*)w;  w += 16 * 4;
    float* be2      = (float*)w;  w += 16 * 4;
    uint2* csr_se   = (uint2*)w;  w += (size_t)E * 8;
    u16* ea16e      = (u16*)w;    w += ((size_t)E * 16 + 1024) * 2;
    uint2* bbuf     = (uint2*)w;  w += (size_t)NB * CAP * 8;

    float* outp = (float*)d_out;
    float* atom = outp + G;

    int eB = (E + EPB - 1) / EPB;
    int qBlocks = (N + 63) / 64;
    int aggBlocks = (N + 3) / 4;

    // 8 dispatches, no memset:
    wprep_kernel<<<64, 256, 0, stream>>>(wq1, bq1, wk1, wv1, ws1, we1,
                                         wq2, bq2, wk2, wv2, ws2, we2,
                                         wt1, be1, wt2, be2, bcount);
    bucket_append<<<eB, 256, 0, stream>>>(dstA, srcA, bcount, bbuf,
                                          ea, ea16e, E, NB);
    csr_index<<<NB, 256, 0, stream>>>(bcount, bbuf, row_ptr, csr_se, N, E, NB);

    qkvs_mfma<<<qBlocks, 256, 0, stream>>>(x, wt1, bq1, bk1, bv1, bs1, be1,
                                           qb, kvb, hb, qeb, N, nullptr, 0);
    agg_kernel<<<aggBlocks, 256, 0, stream>>>(qb, kvb, qeb, we1, ea16e, row_ptr, csr_se,
                                              hb, hb, nullptr, nullptr, N);

    qkvs_mfma<<<qBlocks, 256, 0, stream>>>(hb, wt2, bq2, bk2, bv2, bs2, be2,
                                           qb, kvb, atom, qeb, N, pooled, G * 64);
    agg_kernel<<<aggBlocks, 256, 0, stream>>>(qb, kvb, qeb, we2, ea16e, row_ptr, csr_se,
                                              atom, atom, batch, pooled, N);

    head_kernel<<<G, 64, 0, stream>>>(pooled, wf1, bf1, wf2, bf2, outp, G);
}